// Round 7
// baseline (249.711 us; speedup 1.0000x reference)
//
#include <hip/hip_runtime.h>
#include <hip/hip_bf16.h>

#define DEVINL __device__ __forceinline__

typedef float  f32x4_t  __attribute__((ext_vector_type(4)));
typedef float  f32x16_t __attribute__((ext_vector_type(16)));
typedef short  bf16x8_t __attribute__((ext_vector_type(8)));

#define MFMA16(a,b,c) __builtin_amdgcn_mfma_f32_16x16x32_bf16((a),(b),(c),0,0,0)
#define MFMA32(a,b,c) __builtin_amdgcn_mfma_f32_32x32x16_bf16((a),(b),(c),0,0,0)

DEVINL unsigned short f2bf(float f) {
  union { float f; unsigned u; } v; v.f = f;
  unsigned r = v.u + 0x7fffu + ((v.u >> 16) & 1u);   // round-to-nearest-even
  return (unsigned short)(r >> 16);
}

DEVINL unsigned pk2bf(float lo, float hi) {          // bf16(lo) | bf16(hi)<<16, RNE
  union { __hip_bfloat162 h2; unsigned u; } v;
  v.h2 = __float22bfloat162_rn(make_float2(lo, hi));
  return v.u;
}

// ============================ fragment-order layouts ============================
// I/J (bf16): idx = (rowtile*8 + mc)*512 + r32*16 + h*8 + e
//   rowtile = (global row)>>5 (I rows: i_l*32+x; J rows: j_l*32+y), r32 = row&31,
//   m = mc*16 + h*8 + e.  A/B frag for 32x32x16 = 16B at (r32=lane&31, h=lane>>5).
// W (bf16): idx = (oT*64 + K16)*512 + o32*16 + h*8 + e; o = oT*32+o32.
//   kpos = K16*16 + h*8 + e carries f-element with kpos = y*32 + x (f = x*32+y).
// fl (LDS): row = il*8+jl (32 rows), 1024 kpos; 8-short chunk c stored at
//   cp = c ^ ((c>>2)&7) ^ (row&7)  — <=2-way banks for b64 writes AND b128 reads.

// ---------------- kernel A: LayerNorm + proj + split (+ final_w conversion) ------
__global__ __launch_bounds__(256) void kA(const float* __restrict__ x,
                                          const float* __restrict__ nw,
                                          const float* __restrict__ nb,
                                          const float* __restrict__ pw,
                                          const float* __restrict__ pb,
                                          const float* __restrict__ fw,
                                          unsigned short* __restrict__ Wb,
                                          unsigned short* __restrict__ Ig,
                                          unsigned short* __restrict__ Jg) {
  if (blockIdx.x >= 1024) {                  // final_w fp32 -> bf16, kpos = y*32+x
    int T = (blockIdx.x - 1024) * 256 + threadIdx.x;   // 0..32767
    int o     = T >> 8;
    int kpos0 = (T & 255) * 4;               // 4 consecutive kpos (same y, x-run)
    int y  = kpos0 >> 5;
    int x0 = kpos0 & 31;
    const float* fo = fw + o * 1024 + y;
    ushort4 u;
    u.x = f2bf(fo[(x0 + 0) * 32]);
    u.y = f2bf(fo[(x0 + 1) * 32]);
    u.z = f2bf(fo[(x0 + 2) * 32]);
    u.w = f2bf(fo[(x0 + 3) * 32]);
    size_t off = (size_t)((o >> 5) * 64 + (kpos0 >> 4)) * 512 + (o & 31) * 16
               + ((kpos0 >> 3) & 1) * 8 + (kpos0 & 7);
    *(ushort4*)&Wb[off] = u;
    return;
  }
  __shared__ unsigned short xnl[32 * 264];   // 32 m-rows x 256 ch (+8 pad)
  __shared__ unsigned short pwl[64 * 264];   // 64 d x 256 ch (+8 pad)
  __shared__ unsigned short ep[64 * 36];     // transpose buf: [d][m-local]
  const int tid  = threadIdx.x;
  const int wv   = tid >> 6;
  const int lane = tid & 63;
  const int q    = lane >> 4;
  const int ln16 = lane & 15;
  const int l    = blockIdx.x & 255;
  const int m0   = (blockIdx.x >> 8) * 32;

  const float4* xs = (const float4*)x;
  float4 v[8];
#pragma unroll
  for (int i = 0; i < 8; i++) {
    int row = m0 + i * 4 + wv;
    v[i] = xs[row * 16384 + l * 64 + lane];
  }
  float4 nw4 = ((const float4*)nw)[lane];
  float4 nb4 = ((const float4*)nb)[lane];

#pragma unroll
  for (int i = 0; i < 8; i++) {
    float s  = v[i].x + v[i].y + v[i].z + v[i].w;
    float ss = v[i].x * v[i].x + v[i].y * v[i].y + v[i].z * v[i].z + v[i].w * v[i].w;
#pragma unroll
    for (int off = 32; off > 0; off >>= 1) {
      s  += __shfl_xor(s, off);
      ss += __shfl_xor(ss, off);
    }
    float mu  = s * (1.0f / 256.0f);
    float var = ss * (1.0f / 256.0f) - mu * mu;
    float rs  = rsqrtf(var + 1e-5f);
    ushort4 u;
    u.x = f2bf((v[i].x - mu) * rs * nw4.x + nb4.x);
    u.y = f2bf((v[i].y - mu) * rs * nw4.y + nb4.y);
    u.z = f2bf((v[i].z - mu) * rs * nw4.z + nb4.z);
    u.w = f2bf((v[i].w - mu) * rs * nw4.w + nb4.w);
    *(ushort4*)&xnl[(i * 4 + wv) * 264 + lane * 4] = u;
  }

  const float4* ps = (const float4*)pw;
#pragma unroll
  for (int i = 0; i < 16; i++) {
    float4 w4 = ps[i * 256 + tid];
    ushort4 u;
    u.x = f2bf(w4.x); u.y = f2bf(w4.y); u.z = f2bf(w4.z); u.w = f2bf(w4.w);
    *(ushort4*)&pwl[(i * 4 + wv) * 264 + lane * 4] = u;
  }
  __syncthreads();

  const int rt = wv & 1;
  const int db = (wv >> 1) * 32;
  f32x4_t acc[2] = {{0.f, 0.f, 0.f, 0.f}, {0.f, 0.f, 0.f, 0.f}};
#pragma unroll
  for (int kc = 0; kc < 8; kc++) {
    bf16x8_t a  = *(const bf16x8_t*)&xnl[(rt * 16 + ln16) * 264 + kc * 32 + q * 8];
    bf16x8_t b0 = *(const bf16x8_t*)&pwl[(db + ln16) * 264 + kc * 32 + q * 8];
    bf16x8_t b1 = *(const bf16x8_t*)&pwl[(db + 16 + ln16) * 264 + kc * 32 + q * 8];
    acc[0] = MFMA16(a, b0, acc[0]);
    acc[1] = MFMA16(a, b1, acc[1]);
  }

#pragma unroll
  for (int t2 = 0; t2 < 2; t2++) {
    int d = db + t2 * 16 + ln16;
    float bias  = pb[d];
    float scale = (d & 1) ? 1.0f : (1.0f / 128.0f);
#pragma unroll
    for (int r = 0; r < 4; r++) {
      int mloc = rt * 16 + q * 4 + r;
      ep[d * 36 + mloc] = f2bf((acc[t2][r] + bias) * scale);
    }
  }
  __syncthreads();

  // frag-order stores: I from even d (h row = x), J from odd d.
  const int h  = tid >> 3;          // 0..31 (x or y)
  const int m4 = tid & 7;           // m = m0 + m4*4
  const size_t off = (size_t)(l * 8 + (m0 >> 4) + (m4 >> 2)) * 512 + h * 16 + ((m4 >> 1) & 1) * 8 + (m4 & 1) * 4;
  ushort4 vi = *(const ushort4*)&ep[(2 * h) * 36 + m4 * 4];
  *(ushort4*)&Ig[off] = vi;
  ushort4 vj = *(const ushort4*)&ep[(2 * h + 1) * 36 + m4 * 4];
  *(ushort4*)&Jg[off] = vj;
}

// ---------------- kernel B: wave-specialized producer/consumer pipeline ----------
// 256 blocks (1/CU) x 512 thr. Block = (p: 4 i_l) x (g: 32 j_l), 8 tiles of 8 jl.
// Waves 0-3 (producers): GEMM1(tile k) -> buf[k&1]; I-frags persistent in regs.
// Waves 4-7 (consumers): GEMM2(tile k-1) from buf[(k-1)&1], full K=1024, direct
// epilogue (no reduction). 1 producer + 1 consumer wave per SIMD. 9 barriers.
__global__ __launch_bounds__(512, 2) void kB(const unsigned short* __restrict__ Ig,
                                             const unsigned short* __restrict__ Jg,
                                             const unsigned short* __restrict__ Wb,
                                             const float* __restrict__ fb,
                                             float* __restrict__ out) {
  extern __shared__ unsigned short fl[];     // 2 x (32 rows x 1024) bf16 = 128 KiB
  const int tid  = threadIdx.x;
  const int w    = tid >> 6;                 // wave 0..7
  const int lane = tid & 63;
  const int ln32 = lane & 31;
  const int h    = lane >> 5;
  const int p    = blockIdx.x >> 2;          // i_l quad 0..63
  const int g    = blockIdx.x & 3;           // tile group; t8 = g*8 + k

  if (w < 4) {
    // ========================= PRODUCER =========================
    bf16x8_t af[4][8];                       // all 4 il tiles, persistent
#pragma unroll
    for (int il = 0; il < 4; il++)
#pragma unroll
      for (int mc = 0; mc < 8; mc++)
        af[il][mc] = *(const bf16x8_t*)&Ig[(size_t)((p * 4 + il) * 8 + mc) * 512 + ln32 * 16 + h * 8];

    for (int k = 0; k < 8; k++) {
      unsigned short* buf = fl + (k & 1) * 32768;
      const int t8 = g * 8 + k;
#pragma unroll
      for (int s = 0; s < 2; s++) {
        const int jll = w * 2 + s;           // local jl 0..7
        const unsigned short* Jb = Jg + (size_t)(t8 * 8 + jll) * 4096 + ln32 * 16 + h * 8;
        bf16x8_t jb[8];
#pragma unroll
        for (int mc = 0; mc < 8; mc++) jb[mc] = *(const bf16x8_t*)&Jb[mc * 512];
#pragma unroll
        for (int il = 0; il < 4; il++) {
          f32x16_t c;
#pragma unroll
          for (int i = 0; i < 16; i++) c[i] = 0.f;
#pragma unroll
          for (int mc = 0; mc < 8; mc++) c = MFMA32(af[il][mc], jb[mc], c);
          const int row = il * 8 + jll;
          unsigned short* fr = buf + row * 1024;
          // lane col y=ln32; reg quad g4 -> x = 8*g4+4h..+3; chunk c = 4y+g4
#pragma unroll
          for (int g4 = 0; g4 < 4; g4++) {
            int cc = 4 * ln32 + g4;
            int cp = cc ^ ((cc >> 2) & 7) ^ (row & 7);
            uint2 pv;
            pv.x = pk2bf(c[4 * g4 + 0], c[4 * g4 + 1]);
            pv.y = pk2bf(c[4 * g4 + 2], c[4 * g4 + 3]);
            *(uint2*)&fr[cp * 8 + h * 4] = pv;
          }
        }
      }
      __syncthreads();                       // publish buf[k&1]
    }
    __syncthreads();                         // final drain phase
  } else {
    // ========================= CONSUMER =========================
    const int ot = w - 4;                    // o-tile 0..3
    const unsigned short* Wp = Wb + (size_t)(ot * 64) * 512 + ln32 * 16 + h * 8;
    const float bias = fb[ot * 32 + ln32];
    __syncthreads();                         // wait tile 0
    for (int k = 1; k <= 8; k++) {
      const unsigned short* buf = fl + ((k - 1) & 1) * 32768;
      const unsigned short* A0  = buf + ln32 * 1024;
      auto lda = [&](int K16) {
        int c  = 2 * K16 + h;
        int cp = c ^ ((c >> 2) & 7) ^ (ln32 & 7);
        return *(const bf16x8_t*)&A0[cp * 8];
      };
      f32x16_t o0, o1;
#pragma unroll
      for (int i = 0; i < 16; i++) { o0[i] = 0.f; o1[i] = 0.f; }
      bf16x8_t ar[2][2], br[2][2];
      ar[0][0] = lda(0);  br[0][0] = *(const bf16x8_t*)&Wp[0];
      ar[1][0] = lda(32); br[1][0] = *(const bf16x8_t*)&Wp[32 * 512];
      ar[0][1] = lda(1);  br[0][1] = *(const bf16x8_t*)&Wp[1 * 512];
      ar[1][1] = lda(33); br[1][1] = *(const bf16x8_t*)&Wp[33 * 512];
#pragma unroll
      for (int K = 0; K < 32; K++) {
        bf16x8_t a0 = ar[0][K & 1], b0 = br[0][K & 1];
        bf16x8_t a1 = ar[1][K & 1], b1 = br[1][K & 1];
        if (K < 30) {
          ar[0][K & 1] = lda(K + 2);
          br[0][K & 1] = *(const bf16x8_t*)&Wp[(K + 2) * 512];
          ar[1][K & 1] = lda(K + 34);
          br[1][K & 1] = *(const bf16x8_t*)&Wp[(K + 34) * 512];
        }
        o0 = MFMA32(a0, b0, o0);
        o1 = MFMA32(a1, b1, o1);
      }
      // epilogue: rows rr = (r&3)+8*(r>>2)+4h -> il = rr>>3, jl = rr&7
      const int t8 = g * 8 + (k - 1);
      float* ob = out + ((size_t)(p * 4) * 256 + t8 * 8) * 128 + ot * 32 + ln32;
#pragma unroll
      for (int r = 0; r < 16; r++) {
        int rr = (r & 3) + 8 * (r >> 2) + 4 * h;
        ob[((rr >> 3) * 256 + (rr & 7)) * 128] = o0[r] + o1[r] + bias;
      }
      __syncthreads();
    }
  }
}

extern "C" void kernel_launch(void* const* d_in, const int* in_sizes, int n_in,
                              void* d_out, int out_size, void* d_ws, size_t ws_size,
                              hipStream_t stream) {
  const float* x1d     = (const float*)d_in[0];
  const float* norm_w  = (const float*)d_in[1];
  const float* norm_b  = (const float*)d_in[2];
  const float* proj_w  = (const float*)d_in[3];
  const float* proj_b  = (const float*)d_in[4];
  const float* final_w = (const float*)d_in[5];
  const float* final_b = (const float*)d_in[6];
  float* outp          = (float*)d_out;

  // workspace carve (bf16): W (128*1024), I (256*32*128), J (256*32*128)
  unsigned short* Wb  = (unsigned short*)d_ws;
  unsigned short* Igp = Wb + 131072;
  unsigned short* Jgp = Igp + 1048576;

  const int kb_lds = 2 * 32 * 1024 * 2;   // 131072 B -> 1 block/CU
  hipFuncSetAttribute((const void*)kB, hipFuncAttributeMaxDynamicSharedMemorySize, kb_lds);

  kA<<<1152, 256, 0, stream>>>(x1d, norm_w, norm_b, proj_w, proj_b, final_w, Wb, Igp, Jgp);
  kB<<<256, 512, kb_lds, stream>>>(Igp, Jgp, Wb, final_b, outp);
}